// Round 1
// baseline (1255.598 us; speedup 1.0000x reference)
//
#include <hip/hip_runtime.h>
#include <hip/hip_bf16.h>
#include <math.h>

#define N_NODES 8192
#define IN_FEATS 512
#define N_EDGES 262144
#define NUM_HEADS 8
#define OUT_FEATS 64
#define HD (NUM_HEADS * OUT_FEATS) /* 512 */
#define TOPK 10
#define NEG_INF -9e15f
#define MAXD 128

// ---------------- GEMM: C[8192,512] = feat[8192,512] @ W[512,512]^T ----------------
__global__ __launch_bounds__(256) void gemm_nt(const float* __restrict__ A,
                                               const float* __restrict__ B,
                                               float* __restrict__ C) {
  __shared__ float As[64][36];
  __shared__ float Bs[64][36];
  int tid = threadIdx.x;
  int brow = blockIdx.x * 64;
  int bcol = blockIdx.y * 64;
  int tx = tid & 15, ty = tid >> 4;
  float acc[4][4];
#pragma unroll
  for (int i = 0; i < 4; i++)
#pragma unroll
    for (int j = 0; j < 4; j++) acc[i][j] = 0.f;

  int lr = tid >> 2;          // 0..63
  int lc = (tid & 3) * 8;     // 0,8,16,24
  for (int k0 = 0; k0 < IN_FEATS; k0 += 32) {
    const float4* ap = (const float4*)(A + (size_t)(brow + lr) * IN_FEATS + k0 + lc);
    float4 a0 = ap[0], a1 = ap[1];
    const float4* bp = (const float4*)(B + (size_t)(bcol + lr) * IN_FEATS + k0 + lc);
    float4 b0 = bp[0], b1 = bp[1];
    *(float4*)&As[lr][lc] = a0; *(float4*)&As[lr][lc + 4] = a1;
    *(float4*)&Bs[lr][lc] = b0; *(float4*)&Bs[lr][lc + 4] = b1;
    __syncthreads();
#pragma unroll
    for (int kk = 0; kk < 32; ++kk) {
      float a[4], b[4];
#pragma unroll
      for (int i = 0; i < 4; i++) a[i] = As[ty * 4 + i][kk];
#pragma unroll
      for (int j = 0; j < 4; j++) b[j] = Bs[tx * 4 + j][kk];
#pragma unroll
      for (int i = 0; i < 4; i++)
#pragma unroll
        for (int j = 0; j < 4; j++) acc[i][j] = fmaf(a[i], b[j], acc[i][j]);
    }
    __syncthreads();
  }
#pragma unroll
  for (int i = 0; i < 4; i++) {
    float4 o = make_float4(acc[i][0], acc[i][1], acc[i][2], acc[i][3]);
    *(float4*)(C + (size_t)(brow + ty * 4 + i) * HD + bcol + tx * 4) = o;
  }
}

// ---------------- CSR build ----------------
__global__ __launch_bounds__(256) void histo(const int* __restrict__ src, const int* __restrict__ dst,
                                             int* __restrict__ cnt_s, int* __restrict__ cnt_d) {
  int e = blockIdx.x * blockDim.x + threadIdx.x;
  if (e < N_EDGES) {
    atomicAdd(&cnt_s[src[e]], 1);
    atomicAdd(&cnt_d[dst[e]], 1);
  }
}

__global__ __launch_bounds__(1024) void scan2(const int* __restrict__ cnt_s, const int* __restrict__ cnt_d,
                                              int* __restrict__ rp_s, int* __restrict__ rp_d) {
  __shared__ int ls[1024];
  const int* cnt = blockIdx.x ? cnt_d : cnt_s;
  int* rp = blockIdx.x ? rp_d : rp_s;
  int t = threadIdx.x;
  int base = t * 8;
  int v[8]; int s = 0;
#pragma unroll
  for (int i = 0; i < 8; i++) { v[i] = cnt[base + i]; s += v[i]; }
  ls[t] = s;
  __syncthreads();
  for (int off = 1; off < 1024; off <<= 1) {
    int x = (t >= off) ? ls[t - off] : 0;
    __syncthreads();
    ls[t] += x;
    __syncthreads();
  }
  int excl = (t == 0) ? 0 : ls[t - 1];
#pragma unroll
  for (int i = 0; i < 8; i++) { rp[base + i] = excl; excl += v[i]; }
  if (t == 1023) rp[N_NODES] = excl;
}

__global__ __launch_bounds__(256) void scatter_csr(const int* __restrict__ src, const int* __restrict__ dst,
                                                   const int* __restrict__ rp_s, const int* __restrict__ rp_d,
                                                   int* __restrict__ fill_s, int* __restrict__ fill_d,
                                                   int* __restrict__ cs, int* __restrict__ cd) {
  int e = blockIdx.x * blockDim.x + threadIdx.x;
  if (e < N_EDGES) {
    int p = rp_s[src[e]] + atomicAdd(&fill_s[src[e]], 1);
    cs[p] = e;
    int q = rp_d[dst[e]] + atomicAdd(&fill_d[dst[e]], 1);
    cd[q] = e;
  }
}

// deterministic order: sort each row's edge ids ascending
__global__ __launch_bounds__(256) void sort_rows(const int* __restrict__ rp_s, const int* __restrict__ rp_d,
                                                 int* __restrict__ cs, int* __restrict__ cd) {
  int r = blockIdx.x * blockDim.x + threadIdx.x;
  const int* rp; int* lst;
  if (r < N_NODES) { rp = rp_s; lst = cs; }
  else if (r < 2 * N_NODES) { rp = rp_d; lst = cd; r -= N_NODES; }
  else return;
  int b = rp[r], e2 = rp[r + 1];
  for (int i = b + 1; i < e2; i++) {
    int x = lst[i];
    int j = i - 1;
    while (j >= b && lst[j] > x) { lst[j + 1] = lst[j]; j--; }
    lst[j + 1] = x;
  }
}

// ---------------- per-edge per-head scores (SDDMM), 1 wave per edge ----------------
__global__ __launch_bounds__(256) void edge_scores(const float* __restrict__ fsrc,
                                                   const int* __restrict__ src, const int* __restrict__ dst,
                                                   const float* __restrict__ trans,
                                                   const int* __restrict__ order,
                                                   float* __restrict__ escore, float* __restrict__ val) {
  int widx = (blockIdx.x * blockDim.x + threadIdx.x) >> 6;
  int lane = threadIdx.x & 63;
  if (widx >= N_EDGES) return;
  int e = order[widx];                 // src-sorted order for gather locality
  int s = src[e], d = dst[e];
  const float4* ps = (const float4*)(fsrc + (size_t)s * HD) + lane * 2;
  const float4* pd = (const float4*)(fsrc + (size_t)d * HD) + lane * 2;
  float4 s0 = ps[0], s1 = ps[1];
  float4 d0 = pd[0], d1 = pd[1];
  float dot = s0.x * d0.x + s0.y * d0.y + s0.z * d0.z + s0.w * d0.w
            + s1.x * d1.x + s1.y * d1.y + s1.z * d1.z + s1.w * d1.w;
  // reduce within 8-lane head group
  dot += __shfl_xor(dot, 1);
  dot += __shfl_xor(dot, 2);
  dot += __shfl_xor(dot, 4);
  int head = lane >> 3;
  bool leader = (lane & 7) == 0;
  if (leader) escore[(size_t)e * 8 + head] = dot;
  float tm = trans[e];
  float x = leader ? dot * tm : 0.f;
  x += __shfl_xor(x, 8);
  x += __shfl_xor(x, 16);
  x += __shfl_xor(x, 32);
  if (lane == 0) val[e] = x;
}

// ---------------- per-src-row top-10 threshold (with duplicate-pair combine) ----------------
__global__ __launch_bounds__(256) void topk_thresh(const int* __restrict__ rp_s, const int* __restrict__ cs,
                                                   const int* __restrict__ dst, const float* __restrict__ val,
                                                   float* __restrict__ thresh) {
  int r = blockIdx.x * blockDim.x + threadIdx.x;
  if (r >= N_NODES) return;
  int b = rp_s[r], e2 = rp_s[r + 1];
  float t[10];
#pragma unroll
  for (int i = 0; i < 10; i++) t[i] = 0.f;  // zeros pad the dense row + clamp >= 0
  for (int i = b; i < e2; i++) {
    int ei = cs[i];
    int di = dst[ei];
    bool dup = false;
    for (int k = b; k < i; k++) if (dst[cs[k]] == di) { dup = true; break; }
    if (dup) continue;
    float vsum = val[ei];
    for (int k = i + 1; k < e2; k++) { int ek = cs[k]; if (dst[ek] == di) vsum += val[ek]; }
    if (vsum > t[9]) {
      t[9] = vsum;
#pragma unroll
      for (int j = 9; j > 0; j--) if (t[j] > t[j - 1]) { float tmp = t[j]; t[j] = t[j - 1]; t[j - 1] = tmp; }
    }
  }
  thresh[r] = t[9];
}

// ---------------- per-dst-node: mask + edge softmax + aggregation. 1 wave per node ----------------
__global__ __launch_bounds__(64) void dst_softmax_agg(const int* __restrict__ rp_d, const int* __restrict__ cd,
                                                      const int* __restrict__ rp_s, const int* __restrict__ cs,
                                                      const int* __restrict__ src, const int* __restrict__ dst,
                                                      const float* __restrict__ val, const float* __restrict__ thresh,
                                                      const float* __restrict__ escore,
                                                      const float* __restrict__ fsrc,
                                                      float* __restrict__ out) {
  __shared__ float p_lds[MAXD * 9];
  __shared__ int u_lds[MAXD];
  int v = blockIdx.x;
  int lane = threadIdx.x;
  int rb = rp_d[v], re = rp_d[v + 1];
  int d = re - rb;
  if (d > MAXD) d = MAXD;  // Poisson(32): practically unreachable
  int sb = rp_s[v], se = rp_s[v + 1];
  float th = thresh[v];

  float sc[2][8];
  float m[8];
#pragma unroll
  for (int h = 0; h < 8; h++) m[h] = -3.0e38f;

#pragma unroll
  for (int k = 0; k < 2; k++) {
    int il = lane + 64 * k;
    if (il < d) {
      int ei = cd[rb + il];
      int u = src[ei];
      u_lds[il] = u;
      // A[v][u]: combined value of reverse pair, ascending edge order
      float a = 0.f;
      for (int t = sb; t < se; ++t) { int ek = cs[t]; if (dst[ek] == u) a += val[ek]; }
      bool cmask = (a < th);
      const float* sp = escore + (size_t)ei * 8;
      float4 s0 = *(const float4*)sp;
      float4 s1 = *(const float4*)(sp + 4);
      float ss[8] = {s0.x, s0.y, s0.z, s0.w, s1.x, s1.y, s1.z, s1.w};
#pragma unroll
      for (int h = 0; h < 8; h++) {
        float x = cmask ? NEG_INF : ss[h];
        sc[k][h] = x;
        m[h] = fmaxf(m[h], x);
      }
    } else {
#pragma unroll
      for (int h = 0; h < 8; h++) sc[k][h] = -3.0e38f;
    }
  }
#pragma unroll
  for (int off = 1; off < 64; off <<= 1)
#pragma unroll
    for (int h = 0; h < 8; h++) m[h] = fmaxf(m[h], __shfl_xor(m[h], off));

  float z[8];
#pragma unroll
  for (int h = 0; h < 8; h++) z[h] = 0.f;
#pragma unroll
  for (int k = 0; k < 2; k++) {
    int il = lane + 64 * k;
    if (il < d) {
#pragma unroll
      for (int h = 0; h < 8; h++) {
        float p = expf(sc[k][h] - m[h]);
        z[h] += p;
        p_lds[il * 9 + h] = p;
      }
    }
  }
#pragma unroll
  for (int off = 1; off < 64; off <<= 1)
#pragma unroll
    for (int h = 0; h < 8; h++) z[h] += __shfl_xor(z[h], off);

  int myh = lane >> 3;
  float zh = 0.f;
#pragma unroll
  for (int h = 0; h < 8; h++) zh = (h == myh) ? z[h] : zh;  // static select, no scratch
  float invZ = (d > 0) ? (1.0f / zh) : 0.f;

  __syncthreads();

  float acc[8];
#pragma unroll
  for (int j = 0; j < 8; j++) acc[j] = 0.f;
  for (int i = 0; i < d; i++) {
    float w = p_lds[i * 9 + myh] * invZ;
    const float* fp = fsrc + (size_t)u_lds[i] * HD + lane * 8;
    float4 f0 = *(const float4*)fp;
    float4 f1 = *(const float4*)(fp + 4);
    acc[0] = fmaf(w, f0.x, acc[0]);
    acc[1] = fmaf(w, f0.y, acc[1]);
    acc[2] = fmaf(w, f0.z, acc[2]);
    acc[3] = fmaf(w, f0.w, acc[3]);
    acc[4] = fmaf(w, f1.x, acc[4]);
    acc[5] = fmaf(w, f1.y, acc[5]);
    acc[6] = fmaf(w, f1.z, acc[6]);
    acc[7] = fmaf(w, f1.w, acc[7]);
  }
  float* op = out + (size_t)v * HD + lane * 8;
  *(float4*)op = make_float4(acc[0], acc[1], acc[2], acc[3]);
  *(float4*)(op + 4) = make_float4(acc[4], acc[5], acc[6], acc[7]);
}

extern "C" void kernel_launch(void* const* d_in, const int* in_sizes, int n_in,
                              void* d_out, int out_size, void* d_ws, size_t ws_size,
                              hipStream_t stream) {
  const float* feat = (const float*)d_in[0];
  const float* fcw = (const float*)d_in[1];
  const float* trans = (const float*)d_in[2];
  const int* src = (const int*)d_in[3];
  const int* dst = (const int*)d_in[4];
  float* out = (float*)d_out;

  char* ws = (char*)d_ws;
  size_t off = 0;
  auto alloc = [&](size_t bytes) -> void* {
    size_t o = off;
    off = (off + bytes + 255) & ~(size_t)255;
    return (void*)(ws + o);
  };
  float* fsrc = (float*)alloc((size_t)N_NODES * HD * 4);
  float* escore = (float*)alloc((size_t)N_EDGES * 8 * 4);
  float* val = (float*)alloc((size_t)N_EDGES * 4);
  int* cnt = (int*)alloc((size_t)4 * N_NODES * 4);  // cnt_s, cnt_d, fill_s, fill_d
  int* rp_s = (int*)alloc((size_t)(N_NODES + 1) * 4);
  int* rp_d = (int*)alloc((size_t)(N_NODES + 1) * 4);
  int* cs = (int*)alloc((size_t)N_EDGES * 4);
  int* cd = (int*)alloc((size_t)N_EDGES * 4);
  float* thresh = (float*)alloc((size_t)N_NODES * 4);
  if (off > ws_size) return;  // workspace too small; fail loudly via validation

  int* cnt_s = cnt;
  int* cnt_d = cnt + N_NODES;
  int* fill_s = cnt + 2 * N_NODES;
  int* fill_d = cnt + 3 * N_NODES;

  hipMemsetAsync(cnt, 0, (size_t)4 * N_NODES * 4, stream);
  histo<<<N_EDGES / 256, 256, 0, stream>>>(src, dst, cnt_s, cnt_d);
  scan2<<<2, 1024, 0, stream>>>(cnt_s, cnt_d, rp_s, rp_d);
  scatter_csr<<<N_EDGES / 256, 256, 0, stream>>>(src, dst, rp_s, rp_d, fill_s, fill_d, cs, cd);
  sort_rows<<<(2 * N_NODES) / 256, 256, 0, stream>>>(rp_s, rp_d, cs, cd);
  gemm_nt<<<dim3(N_NODES / 64, HD / 64), 256, 0, stream>>>(feat, fcw, fsrc);
  edge_scores<<<(N_EDGES * 64) / 256, 256, 0, stream>>>(fsrc, src, dst, trans, cs, escore, val);
  topk_thresh<<<N_NODES / 256, 256, 0, stream>>>(rp_s, cs, dst, val, thresh);
  dst_softmax_agg<<<N_NODES, 64, 0, stream>>>(rp_d, cd, rp_s, cs, src, dst, val, thresh, escore, fsrc, out);
}

// Round 2
// 408.997 us; speedup vs baseline: 3.0699x; 3.0699x over previous
//
#include <hip/hip_runtime.h>
#include <hip/hip_bf16.h>
#include <math.h>

#define N_NODES 8192
#define IN_FEATS 512
#define N_EDGES 262144
#define NUM_HEADS 8
#define OUT_FEATS 64
#define HD (NUM_HEADS * OUT_FEATS) /* 512 */
#define TOPK 10
#define NEG_INF -9e15f
#define MAXD 128
#define EID_MASK 0x3FFFF  /* 18 bits */

// ---------------- GEMM: C[8192,512] = feat[8192,512] @ W[512,512]^T ----------------
__global__ __launch_bounds__(256) void gemm_nt(const float* __restrict__ A,
                                               const float* __restrict__ B,
                                               float* __restrict__ C) {
  __shared__ float As[64][36];
  __shared__ float Bs[64][36];
  int tid = threadIdx.x;
  int brow = blockIdx.x * 64;
  int bcol = blockIdx.y * 64;
  int tx = tid & 15, ty = tid >> 4;
  float acc[4][4];
#pragma unroll
  for (int i = 0; i < 4; i++)
#pragma unroll
    for (int j = 0; j < 4; j++) acc[i][j] = 0.f;

  int lr = tid >> 2;          // 0..63
  int lc = (tid & 3) * 8;     // 0,8,16,24
  for (int k0 = 0; k0 < IN_FEATS; k0 += 32) {
    const float4* ap = (const float4*)(A + (size_t)(brow + lr) * IN_FEATS + k0 + lc);
    float4 a0 = ap[0], a1 = ap[1];
    const float4* bp = (const float4*)(B + (size_t)(bcol + lr) * IN_FEATS + k0 + lc);
    float4 b0 = bp[0], b1 = bp[1];
    *(float4*)&As[lr][lc] = a0; *(float4*)&As[lr][lc + 4] = a1;
    *(float4*)&Bs[lr][lc] = b0; *(float4*)&Bs[lr][lc + 4] = b1;
    __syncthreads();
#pragma unroll
    for (int kk = 0; kk < 32; ++kk) {
      float a[4], b[4];
#pragma unroll
      for (int i = 0; i < 4; i++) a[i] = As[ty * 4 + i][kk];
#pragma unroll
      for (int j = 0; j < 4; j++) b[j] = Bs[tx * 4 + j][kk];
#pragma unroll
      for (int i = 0; i < 4; i++)
#pragma unroll
        for (int j = 0; j < 4; j++) acc[i][j] = fmaf(a[i], b[j], acc[i][j]);
    }
    __syncthreads();
  }
#pragma unroll
  for (int i = 0; i < 4; i++) {
    float4 o = make_float4(acc[i][0], acc[i][1], acc[i][2], acc[i][3]);
    *(float4*)(C + (size_t)(brow + ty * 4 + i) * HD + bcol + tx * 4) = o;
  }
}

// ---------------- CSR build ----------------
__global__ __launch_bounds__(256) void histo(const int* __restrict__ src, const int* __restrict__ dst,
                                             int* __restrict__ cnt_s, int* __restrict__ cnt_d) {
  int e = blockIdx.x * blockDim.x + threadIdx.x;
  if (e < N_EDGES) {
    atomicAdd(&cnt_s[src[e]], 1);
    atomicAdd(&cnt_d[dst[e]], 1);
  }
}

__global__ __launch_bounds__(1024) void scan2(const int* __restrict__ cnt_s, const int* __restrict__ cnt_d,
                                              int* __restrict__ rp_s, int* __restrict__ rp_d) {
  __shared__ int ls[1024];
  const int* cnt = blockIdx.x ? cnt_d : cnt_s;
  int* rp = blockIdx.x ? rp_d : rp_s;
  int t = threadIdx.x;
  int base = t * 8;
  int v[8]; int s = 0;
#pragma unroll
  for (int i = 0; i < 8; i++) { v[i] = cnt[base + i]; s += v[i]; }
  ls[t] = s;
  __syncthreads();
  for (int off = 1; off < 1024; off <<= 1) {
    int x = (t >= off) ? ls[t - off] : 0;
    __syncthreads();
    ls[t] += x;
    __syncthreads();
  }
  int excl = (t == 0) ? 0 : ls[t - 1];
#pragma unroll
  for (int i = 0; i < 8; i++) { rp[base + i] = excl; excl += v[i]; }
  if (t == 1023) rp[N_NODES] = excl;
}

__global__ __launch_bounds__(256) void scatter_csr(const int* __restrict__ src, const int* __restrict__ dst,
                                                   const int* __restrict__ rp_s, const int* __restrict__ rp_d,
                                                   int* __restrict__ fill_s, int* __restrict__ fill_d,
                                                   int* __restrict__ cs, int* __restrict__ cd) {
  int e = blockIdx.x * blockDim.x + threadIdx.x;
  if (e < N_EDGES) {
    int p = rp_s[src[e]] + atomicAdd(&fill_s[src[e]], 1);
    cs[p] = e;
    int q = rp_d[dst[e]] + atomicAdd(&fill_d[dst[e]], 1);
    cd[q] = e;
  }
}

// ---------------- wave-per-row odd-even sort in LDS ----------------
// rows 0..N-1: src CSR sorted by key=(dst<<18|eid); writes cs (eids) + keys_s (keys)
// rows N..2N-1: dst CSR sorted by eid
__global__ __launch_bounds__(256) void sort_rows_wave(const int* __restrict__ rp_s, const int* __restrict__ rp_d,
                                                      const int* __restrict__ dst,
                                                      int* __restrict__ cs, int* __restrict__ cd,
                                                      int* __restrict__ keys_s) {
  __shared__ int lkey[4][128];
  int wave = (blockIdx.x * blockDim.x + threadIdx.x) >> 6;
  int lane = threadIdx.x & 63;
  int wl = threadIdx.x >> 6;
  int* lk = lkey[wl];
  bool is_s = wave < N_NODES;
  int r = is_s ? wave : wave - N_NODES;
  const int* rp = is_s ? rp_s : rp_d;
  int b = rp[r], e2 = rp[r + 1];
  int len = e2 - b; if (len > 128) len = 128;
  // load + pad
#pragma unroll
  for (int k = 0; k < 2; k++) {
    int i = lane + 64 * k;
    int kv = 0x7FFFFFFF;
    if (i < len) {
      int e = is_s ? cs[b + i] : cd[b + i];
      kv = is_s ? ((dst[e] << 18) | e) : e;
    }
    lk[i] = kv;
  }
  __syncthreads();
  // 128 odd-even transposition passes (uniform across block)
  for (int p = 0; p < 128; p++) {
    int i = 2 * lane + (p & 1);
    if (i + 1 < 128) {
      int a = lk[i], bb = lk[i + 1];
      if (a > bb) { lk[i] = bb; lk[i + 1] = a; }
    }
    __syncthreads();
  }
  // write back
#pragma unroll
  for (int k = 0; k < 2; k++) {
    int i = lane + 64 * k;
    if (i < len) {
      int kv = lk[i];
      if (is_s) { cs[b + i] = kv & EID_MASK; keys_s[b + i] = kv; }
      else cd[b + i] = kv;
    }
  }
}

// ---------------- per-edge per-head scores (SDDMM), wave per SRC ROW ----------------
// src fragment stays in registers across the row's edges (halves gather traffic)
__global__ __launch_bounds__(256) void edge_scores_row(const float* __restrict__ fsrc,
                                                       const int* __restrict__ dst,
                                                       const float* __restrict__ trans,
                                                       const int* __restrict__ rp_s,
                                                       const int* __restrict__ cs,
                                                       float* __restrict__ escore, float* __restrict__ val) {
  int wave = (blockIdx.x * blockDim.x + threadIdx.x) >> 6;
  int lane = threadIdx.x & 63;
  if (wave >= N_NODES) return;
  int b = rp_s[wave], e2 = rp_s[wave + 1];
  if (b == e2) return;
  const float4* ps = (const float4*)(fsrc + (size_t)wave * HD) + lane * 2;
  float4 s0 = ps[0], s1 = ps[1];
  int head = lane >> 3;
  bool leader = (lane & 7) == 0;
  for (int i = b; i < e2; i++) {
    int e = cs[i];
    int d = dst[e];
    const float4* pd = (const float4*)(fsrc + (size_t)d * HD) + lane * 2;
    float4 d0 = pd[0], d1 = pd[1];
    float dot = s0.x * d0.x + s0.y * d0.y + s0.z * d0.z + s0.w * d0.w
              + s1.x * d1.x + s1.y * d1.y + s1.z * d1.z + s1.w * d1.w;
    dot += __shfl_xor(dot, 1);
    dot += __shfl_xor(dot, 2);
    dot += __shfl_xor(dot, 4);
    if (leader) escore[(size_t)e * 8 + head] = dot;
    float x = leader ? dot * trans[e] : 0.f;
    x += __shfl_xor(x, 8);
    x += __shfl_xor(x, 16);
    x += __shfl_xor(x, 32);
    if (lane == 0) val[e] = x;
  }
}

// ---------------- wave-per-row top-10 threshold + run-combined values ----------------
__global__ __launch_bounds__(256) void topk_wave(const int* __restrict__ rp_s,
                                                 const int* __restrict__ keys_s,
                                                 const float* __restrict__ val,
                                                 float* __restrict__ aval,
                                                 float* __restrict__ thresh) {
  int wave = (blockIdx.x * blockDim.x + threadIdx.x) >> 6;
  int lane = threadIdx.x & 63;
  if (wave >= N_NODES) return;
  int b = rp_s[wave], e2 = rp_s[wave + 1];
  int len = e2 - b; if (len > 128) len = 128;
  float c[2];
#pragma unroll
  for (int k = 0; k < 2; k++) {
    int i = lane + 64 * k;
    float cv = 0.f;
    if (i < len) {
      int key = keys_s[b + i];
      int d = key >> 18;
      int prevd = (i == 0) ? -1 : (keys_s[b + i - 1] >> 18);
      if (d != prevd) {
        // run start: combine duplicates (eid-ascending = np.add.at order)
        float s = val[key & EID_MASK];
        for (int j = i + 1; j < len; j++) {
          int kj = keys_s[b + j];
          if ((kj >> 18) != d) break;
          s += val[kj & EID_MASK];
        }
        cv = s;
        aval[b + i] = s;
      } else {
        aval[b + i] = 0.f;
      }
    }
    c[k] = cv;
  }
  // top-10 of {c values + implicit zero pads}: 10 rounds of wave-max + removal
  float t10 = 0.f;
  for (int t = 0; t < 10; t++) {
    float m = fmaxf(c[0], c[1]);
#pragma unroll
    for (int off = 1; off < 64; off <<= 1) m = fmaxf(m, __shfl_xor(m, off));
    if (m <= 0.f) { t10 = 0.f; break; }   // rest of dense row is zeros -> kth <= 0 -> clamp 0
    t10 = m;
    if (t == 9) break;
    unsigned long long b0 = __ballot(c[0] == m);
    if (b0) {
      int l = __ffsll(b0) - 1;
      if (lane == l) c[0] = -1e30f;
    } else {
      unsigned long long b1 = __ballot(c[1] == m);
      int l = __ffsll(b1) - 1;
      if (lane == l) c[1] = -1e30f;
    }
    if (t == 9) break;
  }
  if (lane == 0) thresh[wave] = fmaxf(t10, 0.f);
}

// ---------------- per-edge reverse-pair mask via binary search ----------------
__global__ __launch_bounds__(256) void cond_edges(const int* __restrict__ src, const int* __restrict__ dst,
                                                  const int* __restrict__ rp_s,
                                                  const int* __restrict__ keys_s,
                                                  const float* __restrict__ aval,
                                                  const float* __restrict__ thresh,
                                                  unsigned char* __restrict__ cond) {
  int e = blockIdx.x * blockDim.x + threadIdx.x;
  if (e >= N_EDGES) return;
  int s = src[e], d = dst[e];
  int lo = rp_s[d], hi = rp_s[d + 1];
  int end = hi;
  int target = s << 18;
  while (lo < hi) {
    int mid = (lo + hi) >> 1;
    if (keys_s[mid] < target) lo = mid + 1; else hi = mid;
  }
  float a = 0.f;
  if (lo < end && (keys_s[lo] >> 18) == s) a = aval[lo];  // lower bound == run start
  cond[e] = (a < thresh[d]) ? 1 : 0;
}

// ---------------- per-dst-node: mask + edge softmax + aggregation. 1 wave per node ----------------
__global__ __launch_bounds__(64) void dst_softmax_agg(const int* __restrict__ rp_d, const int* __restrict__ cd,
                                                      const int* __restrict__ src,
                                                      const unsigned char* __restrict__ cond,
                                                      const float* __restrict__ escore,
                                                      const float* __restrict__ fsrc,
                                                      float* __restrict__ out) {
  __shared__ float p_lds[MAXD * 9];
  __shared__ int u_lds[MAXD];
  int v = blockIdx.x;
  int lane = threadIdx.x;
  int rb = rp_d[v], re = rp_d[v + 1];
  int d = re - rb;
  if (d > MAXD) d = MAXD;

  float sc[2][8];
  float m[8];
#pragma unroll
  for (int h = 0; h < 8; h++) m[h] = -3.0e38f;

#pragma unroll
  for (int k = 0; k < 2; k++) {
    int il = lane + 64 * k;
    if (il < d) {
      int ei = cd[rb + il];
      int u = src[ei];
      u_lds[il] = u;
      bool cmask = cond[ei] != 0;
      const float* sp = escore + (size_t)ei * 8;
      float4 s0 = *(const float4*)sp;
      float4 s1 = *(const float4*)(sp + 4);
      float ss[8] = {s0.x, s0.y, s0.z, s0.w, s1.x, s1.y, s1.z, s1.w};
#pragma unroll
      for (int h = 0; h < 8; h++) {
        float x = cmask ? NEG_INF : ss[h];
        sc[k][h] = x;
        m[h] = fmaxf(m[h], x);
      }
    } else {
#pragma unroll
      for (int h = 0; h < 8; h++) sc[k][h] = -3.0e38f;
    }
  }
#pragma unroll
  for (int off = 1; off < 64; off <<= 1)
#pragma unroll
    for (int h = 0; h < 8; h++) m[h] = fmaxf(m[h], __shfl_xor(m[h], off));

  float z[8];
#pragma unroll
  for (int h = 0; h < 8; h++) z[h] = 0.f;
#pragma unroll
  for (int k = 0; k < 2; k++) {
    int il = lane + 64 * k;
    if (il < d) {
#pragma unroll
      for (int h = 0; h < 8; h++) {
        float p = expf(sc[k][h] - m[h]);
        z[h] += p;
        p_lds[il * 9 + h] = p;
      }
    }
  }
#pragma unroll
  for (int off = 1; off < 64; off <<= 1)
#pragma unroll
    for (int h = 0; h < 8; h++) z[h] += __shfl_xor(z[h], off);

  int myh = lane >> 3;
  float zh = 0.f;
#pragma unroll
  for (int h = 0; h < 8; h++) zh = (h == myh) ? z[h] : zh;
  float invZ = (d > 0) ? (1.0f / zh) : 0.f;

  __syncthreads();

  float acc[8];
#pragma unroll
  for (int j = 0; j < 8; j++) acc[j] = 0.f;
  for (int i = 0; i < d; i++) {
    float w = p_lds[i * 9 + myh] * invZ;
    const float* fp = fsrc + (size_t)u_lds[i] * HD + lane * 8;
    float4 f0 = *(const float4*)fp;
    float4 f1 = *(const float4*)(fp + 4);
    acc[0] = fmaf(w, f0.x, acc[0]);
    acc[1] = fmaf(w, f0.y, acc[1]);
    acc[2] = fmaf(w, f0.z, acc[2]);
    acc[3] = fmaf(w, f0.w, acc[3]);
    acc[4] = fmaf(w, f1.x, acc[4]);
    acc[5] = fmaf(w, f1.y, acc[5]);
    acc[6] = fmaf(w, f1.z, acc[6]);
    acc[7] = fmaf(w, f1.w, acc[7]);
  }
  float* op = out + (size_t)v * HD + lane * 8;
  *(float4*)op = make_float4(acc[0], acc[1], acc[2], acc[3]);
  *(float4*)(op + 4) = make_float4(acc[4], acc[5], acc[6], acc[7]);
}

extern "C" void kernel_launch(void* const* d_in, const int* in_sizes, int n_in,
                              void* d_out, int out_size, void* d_ws, size_t ws_size,
                              hipStream_t stream) {
  const float* feat = (const float*)d_in[0];
  const float* fcw = (const float*)d_in[1];
  const float* trans = (const float*)d_in[2];
  const int* src = (const int*)d_in[3];
  const int* dst = (const int*)d_in[4];
  float* out = (float*)d_out;

  char* ws = (char*)d_ws;
  size_t off = 0;
  auto alloc = [&](size_t bytes) -> void* {
    size_t o = off;
    off = (off + bytes + 255) & ~(size_t)255;
    return (void*)(ws + o);
  };
  float* fsrc = (float*)alloc((size_t)N_NODES * HD * 4);
  float* escore = (float*)alloc((size_t)N_EDGES * 8 * 4);
  float* val = (float*)alloc((size_t)N_EDGES * 4);
  int* cnt = (int*)alloc((size_t)4 * N_NODES * 4);
  int* rp_s = (int*)alloc((size_t)(N_NODES + 1) * 4);
  int* rp_d = (int*)alloc((size_t)(N_NODES + 1) * 4);
  int* cs = (int*)alloc((size_t)N_EDGES * 4);
  int* cd = (int*)alloc((size_t)N_EDGES * 4);
  int* keys_s = (int*)alloc((size_t)N_EDGES * 4);
  float* aval = (float*)alloc((size_t)N_EDGES * 4);
  float* thresh = (float*)alloc((size_t)N_NODES * 4);
  unsigned char* cond = (unsigned char*)alloc((size_t)N_EDGES);
  if (off > ws_size) return;

  int* cnt_s = cnt;
  int* cnt_d = cnt + N_NODES;
  int* fill_s = cnt + 2 * N_NODES;
  int* fill_d = cnt + 3 * N_NODES;

  hipMemsetAsync(cnt, 0, (size_t)4 * N_NODES * 4, stream);
  histo<<<N_EDGES / 256, 256, 0, stream>>>(src, dst, cnt_s, cnt_d);
  scan2<<<2, 1024, 0, stream>>>(cnt_s, cnt_d, rp_s, rp_d);
  scatter_csr<<<N_EDGES / 256, 256, 0, stream>>>(src, dst, rp_s, rp_d, fill_s, fill_d, cs, cd);
  sort_rows_wave<<<(2 * N_NODES) / 4, 256, 0, stream>>>(rp_s, rp_d, dst, cs, cd, keys_s);
  gemm_nt<<<dim3(N_NODES / 64, HD / 64), 256, 0, stream>>>(feat, fcw, fsrc);
  edge_scores_row<<<(N_NODES * 64) / 256, 256, 0, stream>>>(fsrc, dst, trans, rp_s, cs, escore, val);
  topk_wave<<<(N_NODES * 64) / 256, 256, 0, stream>>>(rp_s, keys_s, val, aval, thresh);
  cond_edges<<<N_EDGES / 256, 256, 0, stream>>>(src, dst, rp_s, keys_s, aval, thresh, cond);
  dst_softmax_agg<<<N_NODES, 64, 0, stream>>>(rp_d, cd, src, cond, escore, fsrc, out);
}

// Round 3
// 321.449 us; speedup vs baseline: 3.9061x; 1.2724x over previous
//
#include <hip/hip_runtime.h>
#include <hip/hip_bf16.h>
#include <math.h>

#define N_NODES 8192
#define IN_FEATS 512
#define N_EDGES 262144
#define NUM_HEADS 8
#define OUT_FEATS 64
#define HD (NUM_HEADS * OUT_FEATS) /* 512 */
#define TOPK 10
#define NEG_INF -9e15f
#define MAXD 128
#define EID_MASK 0x3FFFF  /* 18 bits */

// ---------------- GEMM: C[8192,512] = feat[8192,512] @ W[512,512]^T ----------------
// 128x128 tile, 256 thr, 8x8/thread, BK=16, XOR-swizzled LDS, b128 reads, double-buffered.
__device__ __forceinline__ int swz(int row, int k4) {
  return k4 ^ (4 * (((row & 7) ^ ((row >> 3) & 7)) & 7));
}

__global__ __launch_bounds__(256) void gemm_nt(const float* __restrict__ A,
                                               const float* __restrict__ B,
                                               float* __restrict__ C) {
  __shared__ float As[2][128][32];
  __shared__ float Bs[2][128][32];
  int tid = threadIdx.x;
  int tx = tid & 15, ty = tid >> 4;
  int brow = blockIdx.x * 128, bcol = blockIdx.y * 128;
  int sr = tid >> 1;            // staging row 0..127
  int skc = (tid & 1) * 8;      // staging k-offset 0 or 8
  const float* gA = A + (size_t)(brow + sr) * IN_FEATS + skc;
  const float* gB = B + (size_t)(bcol + sr) * IN_FEATS + skc;

  float4 ra0 = *(const float4*)gA;
  float4 ra1 = *(const float4*)(gA + 4);
  float4 rb0 = *(const float4*)gB;
  float4 rb1 = *(const float4*)(gB + 4);
  int w0 = swz(sr, skc), w1 = swz(sr, skc + 4);
  *(float4*)&As[0][sr][w0] = ra0; *(float4*)&As[0][sr][w1] = ra1;
  *(float4*)&Bs[0][sr][w0] = rb0; *(float4*)&Bs[0][sr][w1] = rb1;

  float acc[8][8];
#pragma unroll
  for (int i = 0; i < 8; i++)
#pragma unroll
    for (int j = 0; j < 8; j++) acc[i][j] = 0.f;

  int cur = 0;
  const int NT = IN_FEATS / 16;  // 32
  for (int t = 0; t < NT; ++t) {
    if (t + 1 < NT) {
      const float* pA = gA + (t + 1) * 16;
      const float* pB = gB + (t + 1) * 16;
      ra0 = *(const float4*)pA; ra1 = *(const float4*)(pA + 4);
      rb0 = *(const float4*)pB; rb1 = *(const float4*)(pB + 4);
    }
    __syncthreads();
#pragma unroll
    for (int g = 0; g < 4; ++g) {
      float4 av[8], bv[8];
#pragma unroll
      for (int i = 0; i < 8; i++) {
        int r = ty * 8 + i;
        av[i] = *(const float4*)&As[cur][r][swz(r, g * 4)];
      }
#pragma unroll
      for (int j = 0; j < 8; j++) {
        int c = tx * 8 + j;
        bv[j] = *(const float4*)&Bs[cur][c][swz(c, g * 4)];
      }
#pragma unroll
      for (int i = 0; i < 8; i++)
#pragma unroll
        for (int j = 0; j < 8; j++) {
          acc[i][j] = fmaf(av[i].x, bv[j].x, acc[i][j]);
          acc[i][j] = fmaf(av[i].y, bv[j].y, acc[i][j]);
          acc[i][j] = fmaf(av[i].z, bv[j].z, acc[i][j]);
          acc[i][j] = fmaf(av[i].w, bv[j].w, acc[i][j]);
        }
    }
    if (t + 1 < NT) {
      int nb = cur ^ 1;
      *(float4*)&As[nb][sr][w0] = ra0; *(float4*)&As[nb][sr][w1] = ra1;
      *(float4*)&Bs[nb][sr][w0] = rb0; *(float4*)&Bs[nb][sr][w1] = rb1;
    }
    cur ^= 1;
  }
#pragma unroll
  for (int i = 0; i < 8; i++) {
    float* cp = C + (size_t)(brow + ty * 8 + i) * HD + bcol + tx * 8;
    *(float4*)cp = make_float4(acc[i][0], acc[i][1], acc[i][2], acc[i][3]);
    *(float4*)(cp + 4) = make_float4(acc[i][4], acc[i][5], acc[i][6], acc[i][7]);
  }
}

// ---------------- CSR build ----------------
__global__ __launch_bounds__(256) void histo(const int* __restrict__ src, const int* __restrict__ dst,
                                             int* __restrict__ cnt_s, int* __restrict__ cnt_d) {
  int e = blockIdx.x * blockDim.x + threadIdx.x;
  if (e < N_EDGES) {
    atomicAdd(&cnt_s[src[e]], 1);
    atomicAdd(&cnt_d[dst[e]], 1);
  }
}

__global__ __launch_bounds__(1024) void scan2(const int* __restrict__ cnt_s, const int* __restrict__ cnt_d,
                                              int* __restrict__ rp_s, int* __restrict__ rp_d) {
  __shared__ int ls[1024];
  const int* cnt = blockIdx.x ? cnt_d : cnt_s;
  int* rp = blockIdx.x ? rp_d : rp_s;
  int t = threadIdx.x;
  int base = t * 8;
  int v[8]; int s = 0;
#pragma unroll
  for (int i = 0; i < 8; i++) { v[i] = cnt[base + i]; s += v[i]; }
  ls[t] = s;
  __syncthreads();
  for (int off = 1; off < 1024; off <<= 1) {
    int x = (t >= off) ? ls[t - off] : 0;
    __syncthreads();
    ls[t] += x;
    __syncthreads();
  }
  int excl = (t == 0) ? 0 : ls[t - 1];
#pragma unroll
  for (int i = 0; i < 8; i++) { rp[base + i] = excl; excl += v[i]; }
  if (t == 1023) rp[N_NODES] = excl;
}

__global__ __launch_bounds__(256) void scatter_csr(const int* __restrict__ src, const int* __restrict__ dst,
                                                   const int* __restrict__ rp_s, const int* __restrict__ rp_d,
                                                   int* __restrict__ fill_s, int* __restrict__ fill_d,
                                                   int* __restrict__ cs, int* __restrict__ cd) {
  int e = blockIdx.x * blockDim.x + threadIdx.x;
  if (e < N_EDGES) {
    int p = rp_s[src[e]] + atomicAdd(&fill_s[src[e]], 1);
    cs[p] = e;
    int q = rp_d[dst[e]] + atomicAdd(&fill_d[dst[e]], 1);
    cd[q] = e;
  }
}

// ---------------- wave-per-row odd-even sort in LDS (block-max passes) ----------------
__global__ __launch_bounds__(256) void sort_rows_wave(const int* __restrict__ rp_s, const int* __restrict__ rp_d,
                                                      const int* __restrict__ dst,
                                                      int* __restrict__ cs, int* __restrict__ cd,
                                                      int* __restrict__ keys_s) {
  __shared__ int lkey[4][128];
  __shared__ int wlen[4];
  int wave = (blockIdx.x * blockDim.x + threadIdx.x) >> 6;
  int lane = threadIdx.x & 63;
  int wl = threadIdx.x >> 6;
  int* lk = lkey[wl];
  bool is_s = wave < N_NODES;
  int r = is_s ? wave : wave - N_NODES;
  const int* rp = is_s ? rp_s : rp_d;
  int b = rp[r], e2 = rp[r + 1];
  int len = e2 - b; if (len > 128) len = 128;
#pragma unroll
  for (int k = 0; k < 2; k++) {
    int i = lane + 64 * k;
    int kv = 0x7FFFFFFF;
    if (i < len) {
      int e = is_s ? cs[b + i] : cd[b + i];
      kv = is_s ? ((dst[e] << 18) | e) : e;
    }
    lk[i] = kv;
  }
  if (lane == 0) wlen[wl] = len;
  __syncthreads();
  int mx = max(max(wlen[0], wlen[1]), max(wlen[2], wlen[3]));
  for (int p = 0; p < mx; p++) {
    int i = 2 * lane + (p & 1);
    if (i + 1 < 128) {
      int a = lk[i], bb = lk[i + 1];
      if (a > bb) { lk[i] = bb; lk[i + 1] = a; }
    }
    __syncthreads();
  }
#pragma unroll
  for (int k = 0; k < 2; k++) {
    int i = lane + 64 * k;
    if (i < len) {
      int kv = lk[i];
      if (is_s) { cs[b + i] = kv & EID_MASK; keys_s[b + i] = kv; }
      else cd[b + i] = kv;
    }
  }
}

// ---------------- per-edge per-head scores (SDDMM), wave per SRC ROW ----------------
__global__ __launch_bounds__(256) void edge_scores_row(const float* __restrict__ fsrc,
                                                       const int* __restrict__ dst,
                                                       const float* __restrict__ trans,
                                                       const int* __restrict__ rp_s,
                                                       const int* __restrict__ cs,
                                                       float* __restrict__ escore, float* __restrict__ val) {
  int wave = (blockIdx.x * blockDim.x + threadIdx.x) >> 6;
  int lane = threadIdx.x & 63;
  if (wave >= N_NODES) return;
  int b = rp_s[wave], e2 = rp_s[wave + 1];
  if (b == e2) return;
  const float4* ps = (const float4*)(fsrc + (size_t)wave * HD) + lane * 2;
  float4 s0 = ps[0], s1 = ps[1];
  int head = lane >> 3;
  bool leader = (lane & 7) == 0;
  for (int i = b; i < e2; i++) {
    int e = cs[i];
    int d = dst[e];
    const float4* pd = (const float4*)(fsrc + (size_t)d * HD) + lane * 2;
    float4 d0 = pd[0], d1 = pd[1];
    float dot = s0.x * d0.x + s0.y * d0.y + s0.z * d0.z + s0.w * d0.w
              + s1.x * d1.x + s1.y * d1.y + s1.z * d1.z + s1.w * d1.w;
    dot += __shfl_xor(dot, 1);
    dot += __shfl_xor(dot, 2);
    dot += __shfl_xor(dot, 4);
    if (leader) escore[(size_t)e * 8 + head] = dot;
    float x = leader ? dot * trans[e] : 0.f;
    x += __shfl_xor(x, 8);
    x += __shfl_xor(x, 16);
    x += __shfl_xor(x, 32);
    if (lane == 0) val[e] = x;
  }
}

// ---------------- wave-per-row top-10 threshold + run-combined values ----------------
__global__ __launch_bounds__(256) void topk_wave(const int* __restrict__ rp_s,
                                                 const int* __restrict__ keys_s,
                                                 const float* __restrict__ val,
                                                 float* __restrict__ aval,
                                                 float* __restrict__ thresh) {
  int wave = (blockIdx.x * blockDim.x + threadIdx.x) >> 6;
  int lane = threadIdx.x & 63;
  if (wave >= N_NODES) return;
  int b = rp_s[wave], e2 = rp_s[wave + 1];
  int len = e2 - b; if (len > 128) len = 128;
  float c[2];
#pragma unroll
  for (int k = 0; k < 2; k++) {
    int i = lane + 64 * k;
    float cv = 0.f;
    if (i < len) {
      int key = keys_s[b + i];
      int d = key >> 18;
      int prevd = (i == 0) ? -1 : (keys_s[b + i - 1] >> 18);
      if (d != prevd) {
        float s = val[key & EID_MASK];
        for (int j = i + 1; j < len; j++) {
          int kj = keys_s[b + j];
          if ((kj >> 18) != d) break;
          s += val[kj & EID_MASK];
        }
        cv = s;
        aval[b + i] = s;
      } else {
        aval[b + i] = 0.f;
      }
    }
    c[k] = cv;
  }
  float t10 = 0.f;
  for (int t = 0; t < 10; t++) {
    float m = fmaxf(c[0], c[1]);
#pragma unroll
    for (int off = 1; off < 64; off <<= 1) m = fmaxf(m, __shfl_xor(m, off));
    if (m <= 0.f) { t10 = 0.f; break; }
    t10 = m;
    if (t == 9) break;
    unsigned long long b0 = __ballot(c[0] == m);
    if (b0) {
      int l = __ffsll(b0) - 1;
      if (lane == l) c[0] = -1e30f;
    } else {
      unsigned long long b1 = __ballot(c[1] == m);
      int l = __ffsll(b1) - 1;
      if (lane == l) c[1] = -1e30f;
    }
  }
  if (lane == 0) thresh[wave] = fmaxf(t10, 0.f);
}

// ---------------- per-edge reverse-pair mask via binary search ----------------
__global__ __launch_bounds__(256) void cond_edges(const int* __restrict__ src, const int* __restrict__ dst,
                                                  const int* __restrict__ rp_s,
                                                  const int* __restrict__ keys_s,
                                                  const float* __restrict__ aval,
                                                  const float* __restrict__ thresh,
                                                  unsigned char* __restrict__ cond) {
  int e = blockIdx.x * blockDim.x + threadIdx.x;
  if (e >= N_EDGES) return;
  int s = src[e], d = dst[e];
  int lo = rp_s[d], hi = rp_s[d + 1];
  int end = hi;
  int target = s << 18;
  while (lo < hi) {
    int mid = (lo + hi) >> 1;
    if (keys_s[mid] < target) lo = mid + 1; else hi = mid;
  }
  float a = 0.f;
  if (lo < end && (keys_s[lo] >> 18) == s) a = aval[lo];
  cond[e] = (a < thresh[d]) ? 1 : 0;
}

// ---------------- per-dst-node: mask + edge softmax + aggregation. 1 wave per node ----------------
__global__ __launch_bounds__(64) void dst_softmax_agg(const int* __restrict__ rp_d, const int* __restrict__ cd,
                                                      const int* __restrict__ src,
                                                      const unsigned char* __restrict__ cond,
                                                      const float* __restrict__ escore,
                                                      const float* __restrict__ fsrc,
                                                      float* __restrict__ out) {
  __shared__ float p_lds[MAXD * 9];
  __shared__ int u_lds[MAXD];
  int v = blockIdx.x;
  int lane = threadIdx.x;
  int rb = rp_d[v], re = rp_d[v + 1];
  int d = re - rb;
  if (d > MAXD) d = MAXD;

  float sc[2][8];
  float m[8];
#pragma unroll
  for (int h = 0; h < 8; h++) m[h] = -3.0e38f;

#pragma unroll
  for (int k = 0; k < 2; k++) {
    int il = lane + 64 * k;
    if (il < d) {
      int ei = cd[rb + il];
      int u = src[ei];
      u_lds[il] = u;
      bool cmask = cond[ei] != 0;
      const float* sp = escore + (size_t)ei * 8;
      float4 s0 = *(const float4*)sp;
      float4 s1 = *(const float4*)(sp + 4);
      float ss[8] = {s0.x, s0.y, s0.z, s0.w, s1.x, s1.y, s1.z, s1.w};
#pragma unroll
      for (int h = 0; h < 8; h++) {
        float x = cmask ? NEG_INF : ss[h];
        sc[k][h] = x;
        m[h] = fmaxf(m[h], x);
      }
    } else {
#pragma unroll
      for (int h = 0; h < 8; h++) sc[k][h] = -3.0e38f;
    }
  }
#pragma unroll
  for (int off = 1; off < 64; off <<= 1)
#pragma unroll
    for (int h = 0; h < 8; h++) m[h] = fmaxf(m[h], __shfl_xor(m[h], off));

  float z[8];
#pragma unroll
  for (int h = 0; h < 8; h++) z[h] = 0.f;
#pragma unroll
  for (int k = 0; k < 2; k++) {
    int il = lane + 64 * k;
    if (il < d) {
#pragma unroll
      for (int h = 0; h < 8; h++) {
        float p = expf(sc[k][h] - m[h]);
        z[h] += p;
        p_lds[il * 9 + h] = p;
      }
    }
  }
#pragma unroll
  for (int off = 1; off < 64; off <<= 1)
#pragma unroll
    for (int h = 0; h < 8; h++) z[h] += __shfl_xor(z[h], off);

  int myh = lane >> 3;
  float zh = 0.f;
#pragma unroll
  for (int h = 0; h < 8; h++) zh = (h == myh) ? z[h] : zh;
  float invZ = (d > 0) ? (1.0f / zh) : 0.f;

  __syncthreads();

  float acc[8];
#pragma unroll
  for (int j = 0; j < 8; j++) acc[j] = 0.f;
  for (int i = 0; i < d; i++) {
    float w = p_lds[i * 9 + myh] * invZ;
    const float* fp = fsrc + (size_t)u_lds[i] * HD + lane * 8;
    float4 f0 = *(const float4*)fp;
    float4 f1 = *(const float4*)(fp + 4);
    acc[0] = fmaf(w, f0.x, acc[0]);
    acc[1] = fmaf(w, f0.y, acc[1]);
    acc[2] = fmaf(w, f0.z, acc[2]);
    acc[3] = fmaf(w, f0.w, acc[3]);
    acc[4] = fmaf(w, f1.x, acc[4]);
    acc[5] = fmaf(w, f1.y, acc[5]);
    acc[6] = fmaf(w, f1.z, acc[6]);
    acc[7] = fmaf(w, f1.w, acc[7]);
  }
  float* op = out + (size_t)v * HD + lane * 8;
  *(float4*)op = make_float4(acc[0], acc[1], acc[2], acc[3]);
  *(float4*)(op + 4) = make_float4(acc[4], acc[5], acc[6], acc[7]);
}

extern "C" void kernel_launch(void* const* d_in, const int* in_sizes, int n_in,
                              void* d_out, int out_size, void* d_ws, size_t ws_size,
                              hipStream_t stream) {
  const float* feat = (const float*)d_in[0];
  const float* fcw = (const float*)d_in[1];
  const float* trans = (const float*)d_in[2];
  const int* src = (const int*)d_in[3];
  const int* dst = (const int*)d_in[4];
  float* out = (float*)d_out;

  char* ws = (char*)d_ws;
  size_t off = 0;
  auto alloc = [&](size_t bytes) -> void* {
    size_t o = off;
    off = (off + bytes + 255) & ~(size_t)255;
    return (void*)(ws + o);
  };
  float* fsrc = (float*)alloc((size_t)N_NODES * HD * 4);
  float* escore = (float*)alloc((size_t)N_EDGES * 8 * 4);
  float* val = (float*)alloc((size_t)N_EDGES * 4);
  int* cnt = (int*)alloc((size_t)4 * N_NODES * 4);
  int* rp_s = (int*)alloc((size_t)(N_NODES + 1) * 4);
  int* rp_d = (int*)alloc((size_t)(N_NODES + 1) * 4);
  int* cs = (int*)alloc((size_t)N_EDGES * 4);
  int* cd = (int*)alloc((size_t)N_EDGES * 4);
  int* keys_s = (int*)alloc((size_t)N_EDGES * 4);
  float* aval = (float*)alloc((size_t)N_EDGES * 4);
  float* thresh = (float*)alloc((size_t)N_NODES * 4);
  unsigned char* cond = (unsigned char*)alloc((size_t)N_EDGES);
  if (off > ws_size) return;

  int* cnt_s = cnt;
  int* cnt_d = cnt + N_NODES;
  int* fill_s = cnt + 2 * N_NODES;
  int* fill_d = cnt + 3 * N_NODES;

  hipMemsetAsync(cnt, 0, (size_t)4 * N_NODES * 4, stream);
  histo<<<N_EDGES / 256, 256, 0, stream>>>(src, dst, cnt_s, cnt_d);
  scan2<<<2, 1024, 0, stream>>>(cnt_s, cnt_d, rp_s, rp_d);
  scatter_csr<<<N_EDGES / 256, 256, 0, stream>>>(src, dst, rp_s, rp_d, fill_s, fill_d, cs, cd);
  sort_rows_wave<<<(2 * N_NODES) / 4, 256, 0, stream>>>(rp_s, rp_d, dst, cs, cd, keys_s);
  gemm_nt<<<dim3(N_NODES / 128, HD / 128), 256, 0, stream>>>(feat, fcw, fsrc);
  edge_scores_row<<<(N_NODES * 64) / 256, 256, 0, stream>>>(fsrc, dst, trans, rp_s, cs, escore, val);
  topk_wave<<<(N_NODES * 64) / 256, 256, 0, stream>>>(rp_s, keys_s, val, aval, thresh);
  cond_edges<<<N_EDGES / 256, 256, 0, stream>>>(src, dst, rp_s, keys_s, aval, thresh, cond);
  dst_softmax_agg<<<N_NODES, 64, 0, stream>>>(rp_d, cd, src, cond, escore, fsrc, out);
}

// Round 4
// 286.119 us; speedup vs baseline: 4.3884x; 1.1235x over previous
//
#include <hip/hip_runtime.h>
#include <hip/hip_bf16.h>
#include <math.h>

#define N_NODES 8192
#define IN_FEATS 512
#define N_EDGES 262144
#define NUM_HEADS 8
#define OUT_FEATS 64
#define HD (NUM_HEADS * OUT_FEATS) /* 512 */
#define TOPK 10
#define NEG_INF -9e15f
#define MAXD 128
#define EID_MASK 0x3FFFF  /* 18 bits */

// ---------------- GEMM: C[8192,512] = feat[8192,512] @ W[512,512]^T ----------------
// 128x128 tile, 512 thr (8 waves -> 2 waves/SIMD at 1 block/CU), 4x8/thread, BK=16,
// XOR-swizzled LDS, b128 reads, double-buffered, single barrier per K-step.
__device__ __forceinline__ int swz(int row, int k4) {
  return k4 ^ (4 * (((row & 7) ^ ((row >> 3) & 7)) & 7));
}

__global__ __launch_bounds__(512) void gemm_nt(const float* __restrict__ A,
                                               const float* __restrict__ B,
                                               float* __restrict__ C) {
  __shared__ float As[2][128][32];
  __shared__ float Bs[2][128][32];
  int tid = threadIdx.x;
  int tx = tid & 15, ty = tid >> 4;       // tx 0..15 (cols), ty 0..31 (rows)
  int brow = blockIdx.x * 128, bcol = blockIdx.y * 128;
  int sr = tid >> 2;                      // staging row 0..127
  int skc = (tid & 3) * 4;                // staging k-offset 0,4,8,12
  const float* gA = A + (size_t)(brow + sr) * IN_FEATS + skc;
  const float* gB = B + (size_t)(bcol + sr) * IN_FEATS + skc;

  float4 ra = *(const float4*)gA;
  float4 rb = *(const float4*)gB;
  int w0 = swz(sr, skc);
  *(float4*)&As[0][sr][w0] = ra;
  *(float4*)&Bs[0][sr][w0] = rb;

  float acc[4][8];
#pragma unroll
  for (int i = 0; i < 4; i++)
#pragma unroll
    for (int j = 0; j < 8; j++) acc[i][j] = 0.f;

  int cur = 0;
  const int NT = IN_FEATS / 16;  // 32
  for (int t = 0; t < NT; ++t) {
    if (t + 1 < NT) {
      ra = *(const float4*)(gA + (t + 1) * 16);
      rb = *(const float4*)(gB + (t + 1) * 16);
    }
    __syncthreads();
#pragma unroll
    for (int g = 0; g < 4; ++g) {
      float4 av[4], bv[8];
#pragma unroll
      for (int i = 0; i < 4; i++) {
        int r = ty * 4 + i;
        av[i] = *(const float4*)&As[cur][r][swz(r, g * 4)];
      }
#pragma unroll
      for (int j = 0; j < 8; j++) {
        int c = tx * 8 + j;
        bv[j] = *(const float4*)&Bs[cur][c][swz(c, g * 4)];
      }
#pragma unroll
      for (int i = 0; i < 4; i++)
#pragma unroll
        for (int j = 0; j < 8; j++) {
          acc[i][j] = fmaf(av[i].x, bv[j].x, acc[i][j]);
          acc[i][j] = fmaf(av[i].y, bv[j].y, acc[i][j]);
          acc[i][j] = fmaf(av[i].z, bv[j].z, acc[i][j]);
          acc[i][j] = fmaf(av[i].w, bv[j].w, acc[i][j]);
        }
    }
    if (t + 1 < NT) {
      int nb = cur ^ 1;
      *(float4*)&As[nb][sr][w0] = ra;
      *(float4*)&Bs[nb][sr][w0] = rb;
    }
    cur ^= 1;
  }
#pragma unroll
  for (int i = 0; i < 4; i++) {
    float* cp = C + (size_t)(brow + ty * 4 + i) * HD + bcol + tx * 8;
    *(float4*)cp = make_float4(acc[i][0], acc[i][1], acc[i][2], acc[i][3]);
    *(float4*)(cp + 4) = make_float4(acc[i][4], acc[i][5], acc[i][6], acc[i][7]);
  }
}

// ---------------- f32 -> bf16 copy of fsrc (aggregation-only precision) ----------------
__global__ __launch_bounds__(256) void cvt_bf16(const float* __restrict__ in,
                                                ushort* __restrict__ out) {
  int i = blockIdx.x * blockDim.x + threadIdx.x;  // one per 8 elements
  const float4* p = (const float4*)(in + (size_t)i * 8);
  float4 a = p[0], b = p[1];
  float v[8] = {a.x, a.y, a.z, a.w, b.x, b.y, b.z, b.w};
  ushort u[8];
#pragma unroll
  for (int j = 0; j < 8; j++) {
    u[j] = (ushort)(__bfloat16_as_ushort(__float2bfloat16(v[j])));
  }
  uint4 q;
  q.x = (unsigned)u[0] | ((unsigned)u[1] << 16);
  q.y = (unsigned)u[2] | ((unsigned)u[3] << 16);
  q.z = (unsigned)u[4] | ((unsigned)u[5] << 16);
  q.w = (unsigned)u[6] | ((unsigned)u[7] << 16);
  *(uint4*)(out + (size_t)i * 8) = q;
}

// ---------------- CSR build ----------------
__global__ __launch_bounds__(256) void histo(const int* __restrict__ src, const int* __restrict__ dst,
                                             int* __restrict__ cnt_s, int* __restrict__ cnt_d) {
  int e = blockIdx.x * blockDim.x + threadIdx.x;
  if (e < N_EDGES) {
    atomicAdd(&cnt_s[src[e]], 1);
    atomicAdd(&cnt_d[dst[e]], 1);
  }
}

__global__ __launch_bounds__(1024) void scan2(const int* __restrict__ cnt_s, const int* __restrict__ cnt_d,
                                              int* __restrict__ rp_s, int* __restrict__ rp_d) {
  __shared__ int ls[1024];
  const int* cnt = blockIdx.x ? cnt_d : cnt_s;
  int* rp = blockIdx.x ? rp_d : rp_s;
  int t = threadIdx.x;
  int base = t * 8;
  int v[8]; int s = 0;
#pragma unroll
  for (int i = 0; i < 8; i++) { v[i] = cnt[base + i]; s += v[i]; }
  ls[t] = s;
  __syncthreads();
  for (int off = 1; off < 1024; off <<= 1) {
    int x = (t >= off) ? ls[t - off] : 0;
    __syncthreads();
    ls[t] += x;
    __syncthreads();
  }
  int excl = (t == 0) ? 0 : ls[t - 1];
#pragma unroll
  for (int i = 0; i < 8; i++) { rp[base + i] = excl; excl += v[i]; }
  if (t == 1023) rp[N_NODES] = excl;
}

__global__ __launch_bounds__(256) void scatter_csr(const int* __restrict__ src, const int* __restrict__ dst,
                                                   const int* __restrict__ rp_s, const int* __restrict__ rp_d,
                                                   int* __restrict__ fill_s, int* __restrict__ fill_d,
                                                   int* __restrict__ cs, int* __restrict__ cd) {
  int e = blockIdx.x * blockDim.x + threadIdx.x;
  if (e < N_EDGES) {
    int p = rp_s[src[e]] + atomicAdd(&fill_s[src[e]], 1);
    cs[p] = e;
    int q = rp_d[dst[e]] + atomicAdd(&fill_d[dst[e]], 1);
    cd[q] = e;
  }
}

// ---------------- wave-per-row odd-even sort in LDS (block-max passes) ----------------
__global__ __launch_bounds__(256) void sort_rows_wave(const int* __restrict__ rp_s, const int* __restrict__ rp_d,
                                                      const int* __restrict__ dst,
                                                      int* __restrict__ cs, int* __restrict__ cd,
                                                      int* __restrict__ keys_s) {
  __shared__ int lkey[4][128];
  __shared__ int wlen[4];
  int wave = (blockIdx.x * blockDim.x + threadIdx.x) >> 6;
  int lane = threadIdx.x & 63;
  int wl = threadIdx.x >> 6;
  int* lk = lkey[wl];
  bool is_s = wave < N_NODES;
  int r = is_s ? wave : wave - N_NODES;
  const int* rp = is_s ? rp_s : rp_d;
  int b = rp[r], e2 = rp[r + 1];
  int len = e2 - b; if (len > 128) len = 128;
#pragma unroll
  for (int k = 0; k < 2; k++) {
    int i = lane + 64 * k;
    int kv = 0x7FFFFFFF;
    if (i < len) {
      int e = is_s ? cs[b + i] : cd[b + i];
      kv = is_s ? ((dst[e] << 18) | e) : e;
    }
    lk[i] = kv;
  }
  if (lane == 0) wlen[wl] = len;
  __syncthreads();
  int mx = max(max(wlen[0], wlen[1]), max(wlen[2], wlen[3]));
  for (int p = 0; p < mx; p++) {
    int i = 2 * lane + (p & 1);
    if (i + 1 < 128) {
      int a = lk[i], bb = lk[i + 1];
      if (a > bb) { lk[i] = bb; lk[i + 1] = a; }
    }
    __syncthreads();
  }
#pragma unroll
  for (int k = 0; k < 2; k++) {
    int i = lane + 64 * k;
    if (i < len) {
      int kv = lk[i];
      if (is_s) { cs[b + i] = kv & EID_MASK; keys_s[b + i] = kv; }
      else cd[b + i] = kv;
    }
  }
}

// ---------------- per-edge per-head scores (SDDMM), wave per SRC ROW ----------------
__global__ __launch_bounds__(256) void edge_scores_row(const float* __restrict__ fsrc,
                                                       const int* __restrict__ dst,
                                                       const float* __restrict__ trans,
                                                       const int* __restrict__ rp_s,
                                                       const int* __restrict__ cs,
                                                       float* __restrict__ escore, float* __restrict__ val) {
  int wave = (blockIdx.x * blockDim.x + threadIdx.x) >> 6;
  int lane = threadIdx.x & 63;
  if (wave >= N_NODES) return;
  int b = rp_s[wave], e2 = rp_s[wave + 1];
  if (b == e2) return;
  const float4* ps = (const float4*)(fsrc + (size_t)wave * HD) + lane * 2;
  float4 s0 = ps[0], s1 = ps[1];
  int head = lane >> 3;
  bool leader = (lane & 7) == 0;
  for (int i = b; i < e2; i++) {
    int e = cs[i];
    int d = dst[e];
    const float4* pd = (const float4*)(fsrc + (size_t)d * HD) + lane * 2;
    float4 d0 = pd[0], d1 = pd[1];
    float dot = s0.x * d0.x + s0.y * d0.y + s0.z * d0.z + s0.w * d0.w
              + s1.x * d1.x + s1.y * d1.y + s1.z * d1.z + s1.w * d1.w;
    dot += __shfl_xor(dot, 1);
    dot += __shfl_xor(dot, 2);
    dot += __shfl_xor(dot, 4);
    if (leader) escore[(size_t)e * 8 + head] = dot;
    float x = leader ? dot * trans[e] : 0.f;
    x += __shfl_xor(x, 8);
    x += __shfl_xor(x, 16);
    x += __shfl_xor(x, 32);
    if (lane == 0) val[e] = x;
  }
}

// ---------------- wave-per-row top-10 threshold + run-combined values ----------------
__global__ __launch_bounds__(256) void topk_wave(const int* __restrict__ rp_s,
                                                 const int* __restrict__ keys_s,
                                                 const float* __restrict__ val,
                                                 float* __restrict__ aval,
                                                 float* __restrict__ thresh) {
  int wave = (blockIdx.x * blockDim.x + threadIdx.x) >> 6;
  int lane = threadIdx.x & 63;
  if (wave >= N_NODES) return;
  int b = rp_s[wave], e2 = rp_s[wave + 1];
  int len = e2 - b; if (len > 128) len = 128;
  float c[2];
#pragma unroll
  for (int k = 0; k < 2; k++) {
    int i = lane + 64 * k;
    float cv = 0.f;
    if (i < len) {
      int key = keys_s[b + i];
      int d = key >> 18;
      int prevd = (i == 0) ? -1 : (keys_s[b + i - 1] >> 18);
      if (d != prevd) {
        float s = val[key & EID_MASK];
        for (int j = i + 1; j < len; j++) {
          int kj = keys_s[b + j];
          if ((kj >> 18) != d) break;
          s += val[kj & EID_MASK];
        }
        cv = s;
        aval[b + i] = s;
      } else {
        aval[b + i] = 0.f;
      }
    }
    c[k] = cv;
  }
  float t10 = 0.f;
  for (int t = 0; t < 10; t++) {
    float m = fmaxf(c[0], c[1]);
#pragma unroll
    for (int off = 1; off < 64; off <<= 1) m = fmaxf(m, __shfl_xor(m, off));
    if (m <= 0.f) { t10 = 0.f; break; }
    t10 = m;
    if (t == 9) break;
    unsigned long long b0 = __ballot(c[0] == m);
    if (b0) {
      int l = __ffsll(b0) - 1;
      if (lane == l) c[0] = -1e30f;
    } else {
      unsigned long long b1 = __ballot(c[1] == m);
      int l = __ffsll(b1) - 1;
      if (lane == l) c[1] = -1e30f;
    }
  }
  if (lane == 0) thresh[wave] = fmaxf(t10, 0.f);
}

// ---------------- per-edge reverse-pair mask via binary search ----------------
__global__ __launch_bounds__(256) void cond_edges(const int* __restrict__ src, const int* __restrict__ dst,
                                                  const int* __restrict__ rp_s,
                                                  const int* __restrict__ keys_s,
                                                  const float* __restrict__ aval,
                                                  const float* __restrict__ thresh,
                                                  unsigned char* __restrict__ cond) {
  int e = blockIdx.x * blockDim.x + threadIdx.x;
  if (e >= N_EDGES) return;
  int s = src[e], d = dst[e];
  int lo = rp_s[d], hi = rp_s[d + 1];
  int end = hi;
  int target = s << 18;
  while (lo < hi) {
    int mid = (lo + hi) >> 1;
    if (keys_s[mid] < target) lo = mid + 1; else hi = mid;
  }
  float a = 0.f;
  if (lo < end && (keys_s[lo] >> 18) == s) a = aval[lo];
  cond[e] = (a < thresh[d]) ? 1 : 0;
}

// ---------------- per-dst-node: mask + edge softmax + aggregation (bf16 gather) ----------------
__global__ __launch_bounds__(64) void dst_softmax_agg(const int* __restrict__ rp_d, const int* __restrict__ cd,
                                                      const int* __restrict__ src,
                                                      const unsigned char* __restrict__ cond,
                                                      const float* __restrict__ escore,
                                                      const ushort* __restrict__ fsrc16,
                                                      float* __restrict__ out) {
  __shared__ float p_lds[MAXD * 9];
  __shared__ int u_lds[MAXD];
  int v = blockIdx.x;
  int lane = threadIdx.x;
  int rb = rp_d[v], re = rp_d[v + 1];
  int d = re - rb;
  if (d > MAXD) d = MAXD;

  float sc[2][8];
  float m[8];
#pragma unroll
  for (int h = 0; h < 8; h++) m[h] = -3.0e38f;

#pragma unroll
  for (int k = 0; k < 2; k++) {
    int il = lane + 64 * k;
    if (il < d) {
      int ei = cd[rb + il];
      int u = src[ei];
      u_lds[il] = u;
      bool cmask = cond[ei] != 0;
      const float* sp = escore + (size_t)ei * 8;
      float4 s0 = *(const float4*)sp;
      float4 s1 = *(const float4*)(sp + 4);
      float ss[8] = {s0.x, s0.y, s0.z, s0.w, s1.x, s1.y, s1.z, s1.w};
#pragma unroll
      for (int h = 0; h < 8; h++) {
        float x = cmask ? NEG_INF : ss[h];
        sc[k][h] = x;
        m[h] = fmaxf(m[h], x);
      }
    } else {
#pragma unroll
      for (int h = 0; h < 8; h++) sc[k][h] = -3.0e38f;
    }
  }
#pragma unroll
  for (int off = 1; off < 64; off <<= 1)
#pragma unroll
    for (int h = 0; h < 8; h++) m[h] = fmaxf(m[h], __shfl_xor(m[h], off));

  float z[8];
#pragma unroll
  for (int h = 0; h < 8; h++) z[h] = 0.f;
#pragma unroll
  for (int k = 0; k < 2; k++) {
    int il = lane + 64 * k;
    if (il < d) {
#pragma unroll
      for (int h = 0; h < 8; h++) {
        float p = expf(sc[k][h] - m[h]);
        z[h] += p;
        p_lds[il * 9 + h] = p;
      }
    }
  }
#pragma unroll
  for (int off = 1; off < 64; off <<= 1)
#pragma unroll
    for (int h = 0; h < 8; h++) z[h] += __shfl_xor(z[h], off);

  int myh = lane >> 3;
  float zh = 0.f;
#pragma unroll
  for (int h = 0; h < 8; h++) zh = (h == myh) ? z[h] : zh;
  float invZ = (d > 0) ? (1.0f / zh) : 0.f;

  __syncthreads();

  float acc[8];
#pragma unroll
  for (int j = 0; j < 8; j++) acc[j] = 0.f;
  for (int i = 0; i < d; i++) {
    float w = p_lds[i * 9 + myh] * invZ;
    const ushort* fp = fsrc16 + (size_t)u_lds[i] * HD + lane * 8;
    uint4 q = *(const uint4*)fp;
    acc[0] = fmaf(w, __uint_as_float(q.x << 16), acc[0]);
    acc[1] = fmaf(w, __uint_as_float(q.x & 0xFFFF0000u), acc[1]);
    acc[2] = fmaf(w, __uint_as_float(q.y << 16), acc[2]);
    acc[3] = fmaf(w, __uint_as_float(q.y & 0xFFFF0000u), acc[3]);
    acc[4] = fmaf(w, __uint_as_float(q.z << 16), acc[4]);
    acc[5] = fmaf(w, __uint_as_float(q.z & 0xFFFF0000u), acc[5]);
    acc[6] = fmaf(w, __uint_as_float(q.w << 16), acc[6]);
    acc[7] = fmaf(w, __uint_as_float(q.w & 0xFFFF0000u), acc[7]);
  }
  float* op = out + (size_t)v * HD + lane * 8;
  *(float4*)op = make_float4(acc[0], acc[1], acc[2], acc[3]);
  *(float4*)(op + 4) = make_float4(acc[4], acc[5], acc[6], acc[7]);
}

extern "C" void kernel_launch(void* const* d_in, const int* in_sizes, int n_in,
                              void* d_out, int out_size, void* d_ws, size_t ws_size,
                              hipStream_t stream) {
  const float* feat = (const float*)d_in[0];
  const float* fcw = (const float*)d_in[1];
  const float* trans = (const float*)d_in[2];
  const int* src = (const int*)d_in[3];
  const int* dst = (const int*)d_in[4];
  float* out = (float*)d_out;

  char* ws = (char*)d_ws;
  size_t off = 0;
  auto alloc = [&](size_t bytes) -> void* {
    size_t o = off;
    off = (off + bytes + 255) & ~(size_t)255;
    return (void*)(ws + o);
  };
  float* fsrc = (float*)alloc((size_t)N_NODES * HD * 4);
  ushort* fsrc16 = (ushort*)alloc((size_t)N_NODES * HD * 2);
  float* escore = (float*)alloc((size_t)N_EDGES * 8 * 4);
  float* val = (float*)alloc((size_t)N_EDGES * 4);
  int* cnt = (int*)alloc((size_t)4 * N_NODES * 4);
  int* rp_s = (int*)alloc((size_t)(N_NODES + 1) * 4);
  int* rp_d = (int*)alloc((size_t)(N_NODES + 1) * 4);
  int* cs = (int*)alloc((size_t)N_EDGES * 4);
  int* cd = (int*)alloc((size_t)N_EDGES * 4);
  int* keys_s = (int*)alloc((size_t)N_EDGES * 4);
  float* aval = (float*)alloc((size_t)N_EDGES * 4);
  float* thresh = (float*)alloc((size_t)N_NODES * 4);
  unsigned char* cond = (unsigned char*)alloc((size_t)N_EDGES);
  if (off > ws_size) return;

  int* cnt_s = cnt;
  int* cnt_d = cnt + N_NODES;
  int* fill_s = cnt + 2 * N_NODES;
  int* fill_d = cnt + 3 * N_NODES;

  hipMemsetAsync(cnt, 0, (size_t)4 * N_NODES * 4, stream);
  histo<<<N_EDGES / 256, 256, 0, stream>>>(src, dst, cnt_s, cnt_d);
  scan2<<<2, 1024, 0, stream>>>(cnt_s, cnt_d, rp_s, rp_d);
  scatter_csr<<<N_EDGES / 256, 256, 0, stream>>>(src, dst, rp_s, rp_d, fill_s, fill_d, cs, cd);
  sort_rows_wave<<<(2 * N_NODES) / 4, 256, 0, stream>>>(rp_s, rp_d, dst, cs, cd, keys_s);
  gemm_nt<<<dim3(N_NODES / 128, HD / 128), 512, 0, stream>>>(feat, fcw, fsrc);
  cvt_bf16<<<(N_NODES * HD / 8) / 256, 256, 0, stream>>>(fsrc, fsrc16);
  edge_scores_row<<<(N_NODES * 64) / 256, 256, 0, stream>>>(fsrc, dst, trans, rp_s, cs, escore, val);
  topk_wave<<<(N_NODES * 64) / 256, 256, 0, stream>>>(rp_s, keys_s, val, aval, thresh);
  cond_edges<<<N_EDGES / 256, 256, 0, stream>>>(src, dst, rp_s, keys_s, aval, thresh, cond);
  dst_softmax_agg<<<N_NODES, 64, 0, stream>>>(rp_d, cd, src, cond, escore, fsrc16, out);
}

// Round 5
// 259.819 us; speedup vs baseline: 4.8326x; 1.1012x over previous
//
#include <hip/hip_runtime.h>
#include <hip/hip_bf16.h>
#include <math.h>

#define N_NODES 8192
#define IN_FEATS 512
#define N_EDGES 262144
#define NUM_HEADS 8
#define OUT_FEATS 64
#define HD (NUM_HEADS * OUT_FEATS) /* 512 */
#define TOPK 10
#define NEG_INF -9e15f
#define MAXD 128
#define EID_MASK 0x3FFFF  /* 18 bits */

// ---------------- GEMM: C[8192,512] = feat[8192,512] @ W[512,512]^T ----------------
// 128x128 tile, 512 thr = 2 sub-blocks of 256; sub s computes K half [s*256, s*256+256).
// 8x8 per-thread fragments (16 FMA per ds_read_b128 -> LDS:VALU = 1.5:1), XOR-swizzled
// single-buffered per-sub LDS tiles (64KB total), deterministic LDS accumulator combine.
// Writes f32 C and bf16 C16 in the epilogue (replaces separate cvt kernel).
__device__ __forceinline__ int swz(int row, int k4) {
  return k4 ^ (4 * (((row & 7) ^ ((row >> 3) & 7)) & 7));
}

__global__ __launch_bounds__(512, 2) void gemm_nt(const float* __restrict__ A,
                                                  const float* __restrict__ B,
                                                  float* __restrict__ C,
                                                  ushort* __restrict__ C16) {
  __shared__ char smem[65536];
  int tid = threadIdx.x;
  int sub = tid >> 8;          // K half
  int stid = tid & 255;
  int tx = stid & 15, ty = stid >> 4;
  int brow = blockIdx.x * 128, bcol = blockIdx.y * 128;
  int kbase = sub * 256;

  float (*Asub)[32] = (float(*)[32])(smem + sub * 16384);           // [128][32]
  float (*Bsub)[32] = (float(*)[32])(smem + 32768 + sub * 16384);   // [128][32]

  int sr = stid >> 1;          // staging row 0..127
  int skc = (stid & 1) * 8;    // staging k-offset 0 or 8
  const float* gA = A + (size_t)(brow + sr) * IN_FEATS + kbase + skc;
  const float* gB = B + (size_t)(bcol + sr) * IN_FEATS + kbase + skc;
  int w0 = swz(sr, skc), w1 = swz(sr, skc + 4);

  float acc[8][8];
#pragma unroll
  for (int i = 0; i < 8; i++)
#pragma unroll
    for (int j = 0; j < 8; j++) acc[i][j] = 0.f;

  float4 ra0 = *(const float4*)gA;
  float4 ra1 = *(const float4*)(gA + 4);
  float4 rb0 = *(const float4*)gB;
  float4 rb1 = *(const float4*)(gB + 4);

  const int NT = 16;  // 256 K per sub / 16
  for (int t = 0; t < NT; ++t) {
    __syncthreads();  // previous compute done before overwrite
    *(float4*)&Asub[sr][w0] = ra0; *(float4*)&Asub[sr][w1] = ra1;
    *(float4*)&Bsub[sr][w0] = rb0; *(float4*)&Bsub[sr][w1] = rb1;
    if (t + 1 < NT) {
      const float* pA = gA + (t + 1) * 16;
      const float* pB = gB + (t + 1) * 16;
      ra0 = *(const float4*)pA; ra1 = *(const float4*)(pA + 4);
      rb0 = *(const float4*)pB; rb1 = *(const float4*)(pB + 4);
    }
    __syncthreads();
#pragma unroll
    for (int g = 0; g < 4; ++g) {
      float4 av[8], bv[8];
#pragma unroll
      for (int i = 0; i < 8; i++) {
        int r = ty * 8 + i;
        av[i] = *(const float4*)&Asub[r][swz(r, g * 4)];
      }
#pragma unroll
      for (int j = 0; j < 8; j++) {
        int c = tx * 8 + j;
        bv[j] = *(const float4*)&Bsub[c][swz(c, g * 4)];
      }
#pragma unroll
      for (int i = 0; i < 8; i++)
#pragma unroll
        for (int j = 0; j < 8; j++) {
          acc[i][j] = fmaf(av[i].x, bv[j].x, acc[i][j]);
          acc[i][j] = fmaf(av[i].y, bv[j].y, acc[i][j]);
          acc[i][j] = fmaf(av[i].z, bv[j].z, acc[i][j]);
          acc[i][j] = fmaf(av[i].w, bv[j].w, acc[i][j]);
        }
    }
  }

  // deterministic combine: acc_total = acc_sub0 + acc_sub1 (exchange via padded LDS)
  float (*xch)[33] = (float(*)[33])smem;  // [256][33] = 33792B, 2-way bank alias (free)
  __syncthreads();
#pragma unroll
  for (int r = 0; r < 2; ++r) {
    if (sub == 1) {
#pragma unroll
      for (int k = 0; k < 32; ++k) {
        int idx = r * 32 + k;
        xch[stid][k] = acc[idx >> 3][idx & 7];
      }
    }
    __syncthreads();
    if (sub == 0) {
#pragma unroll
      for (int k = 0; k < 32; ++k) {
        int idx = r * 32 + k;
        acc[idx >> 3][idx & 7] += xch[stid][k];
      }
    }
    __syncthreads();
  }

  if (sub == 0) {
#pragma unroll
    for (int i = 0; i < 8; i++) {
      int row = brow + ty * 8 + i;
      float* cp = C + (size_t)row * HD + bcol + tx * 8;
      *(float4*)cp = make_float4(acc[i][0], acc[i][1], acc[i][2], acc[i][3]);
      *(float4*)(cp + 4) = make_float4(acc[i][4], acc[i][5], acc[i][6], acc[i][7]);
      ushort u[8];
#pragma unroll
      for (int j = 0; j < 8; j++) u[j] = __bfloat16_as_ushort(__float2bfloat16(acc[i][j]));
      uint4 q;
      q.x = (unsigned)u[0] | ((unsigned)u[1] << 16);
      q.y = (unsigned)u[2] | ((unsigned)u[3] << 16);
      q.z = (unsigned)u[4] | ((unsigned)u[5] << 16);
      q.w = (unsigned)u[6] | ((unsigned)u[7] << 16);
      *(uint4*)(C16 + (size_t)row * HD + bcol + tx * 8) = q;
    }
  }
}

// ---------------- CSR build ----------------
__global__ __launch_bounds__(256) void histo(const int* __restrict__ src, const int* __restrict__ dst,
                                             int* __restrict__ cnt_s, int* __restrict__ cnt_d) {
  int e = blockIdx.x * blockDim.x + threadIdx.x;
  if (e < N_EDGES) {
    atomicAdd(&cnt_s[src[e]], 1);
    atomicAdd(&cnt_d[dst[e]], 1);
  }
}

__global__ __launch_bounds__(1024) void scan2(const int* __restrict__ cnt_s, const int* __restrict__ cnt_d,
                                              int* __restrict__ rp_s, int* __restrict__ rp_d) {
  __shared__ int ls[1024];
  const int* cnt = blockIdx.x ? cnt_d : cnt_s;
  int* rp = blockIdx.x ? rp_d : rp_s;
  int t = threadIdx.x;
  int base = t * 8;
  int v[8]; int s = 0;
#pragma unroll
  for (int i = 0; i < 8; i++) { v[i] = cnt[base + i]; s += v[i]; }
  ls[t] = s;
  __syncthreads();
  for (int off = 1; off < 1024; off <<= 1) {
    int x = (t >= off) ? ls[t - off] : 0;
    __syncthreads();
    ls[t] += x;
    __syncthreads();
  }
  int excl = (t == 0) ? 0 : ls[t - 1];
#pragma unroll
  for (int i = 0; i < 8; i++) { rp[base + i] = excl; excl += v[i]; }
  if (t == 1023) rp[N_NODES] = excl;
}

__global__ __launch_bounds__(256) void scatter_csr(const int* __restrict__ src, const int* __restrict__ dst,
                                                   const int* __restrict__ rp_s, const int* __restrict__ rp_d,
                                                   int* __restrict__ fill_s, int* __restrict__ fill_d,
                                                   int* __restrict__ cs, int* __restrict__ cd) {
  int e = blockIdx.x * blockDim.x + threadIdx.x;
  if (e < N_EDGES) {
    int p = rp_s[src[e]] + atomicAdd(&fill_s[src[e]], 1);
    cs[p] = e;
    int q = rp_d[dst[e]] + atomicAdd(&fill_d[dst[e]], 1);
    cd[q] = e;
  }
}

// ---------------- barrier-free in-wave bitonic sort (128 elems, 2/lane) ----------------
// rows 0..N-1: src CSR sorted by key=(dst<<18|eid); rows N..2N-1: dst CSR by eid.
__global__ __launch_bounds__(256) void sort_rows_bitonic(const int* __restrict__ rp_s,
                                                         const int* __restrict__ rp_d,
                                                         const int* __restrict__ dst,
                                                         int* __restrict__ cs, int* __restrict__ cd,
                                                         int* __restrict__ keys_s) {
  int wave = (blockIdx.x * blockDim.x + threadIdx.x) >> 6;
  int lane = threadIdx.x & 63;
  bool is_s = wave < N_NODES;
  int r = is_s ? wave : wave - N_NODES;
  const int* rp = is_s ? rp_s : rp_d;
  int b = rp[r], e2 = rp[r + 1];
  int len = e2 - b; if (len > 128) len = 128;

  int x0 = 0x7FFFFFFF, x1 = 0x7FFFFFFF;
  if (lane < len) {
    int e = is_s ? cs[b + lane] : cd[b + lane];
    x0 = is_s ? ((dst[e] << 18) | e) : e;
  }
  if (lane + 64 < len) {
    int e = is_s ? cs[b + lane + 64] : cd[b + lane + 64];
    x1 = is_s ? ((dst[e] << 18) | e) : e;
  }

  // bitonic network, positions p0=lane, p1=lane+64
  for (int s = 2; s <= 64; s <<= 1) {
    bool asc1 = ((64 & s) == 0);  // (lane+64)&s == lane&s for s<64; ==s for s==64
    for (int d = s >> 1; d >= 1; d >>= 1) {
      {
        int y = __shfl_xor(x0, d);
        bool keepmin = (((lane & d) == 0) == ((lane & s) == 0));
        x0 = keepmin ? min(x0, y) : max(x0, y);
      }
      {
        int y = __shfl_xor(x1, d);
        bool asc = asc1 ? ((lane & s) == 0) : false;  // s==64 -> descending half
        bool keepmin = (((lane & d) == 0) == asc);
        x1 = keepmin ? min(x1, y) : max(x1, y);
      }
    }
  }
  // s = 128 phase: d=64 is in-register
  { int lo = min(x0, x1), hi = max(x0, x1); x0 = lo; x1 = hi; }
  for (int d = 32; d >= 1; d >>= 1) {
    {
      int y = __shfl_xor(x0, d);
      bool keepmin = ((lane & d) == 0);
      x0 = keepmin ? min(x0, y) : max(x0, y);
    }
    {
      int y = __shfl_xor(x1, d);
      bool keepmin = ((lane & d) == 0);
      x1 = keepmin ? min(x1, y) : max(x1, y);
    }
  }

  if (lane < len) {
    if (is_s) { cs[b + lane] = x0 & EID_MASK; keys_s[b + lane] = x0; }
    else cd[b + lane] = x0;
  }
  if (lane + 64 < len) {
    if (is_s) { cs[b + lane + 64] = x1 & EID_MASK; keys_s[b + lane + 64] = x1; }
    else cd[b + lane + 64] = x1;
  }
}

// ---------------- per-edge per-head scores (SDDMM), wave per SRC ROW ----------------
__global__ __launch_bounds__(256) void edge_scores_row(const float* __restrict__ fsrc,
                                                       const int* __restrict__ dst,
                                                       const float* __restrict__ trans,
                                                       const int* __restrict__ rp_s,
                                                       const int* __restrict__ cs,
                                                       float* __restrict__ escore, float* __restrict__ val) {
  int wave = (blockIdx.x * blockDim.x + threadIdx.x) >> 6;
  int lane = threadIdx.x & 63;
  if (wave >= N_NODES) return;
  int b = rp_s[wave], e2 = rp_s[wave + 1];
  if (b == e2) return;
  const float4* ps = (const float4*)(fsrc + (size_t)wave * HD) + lane * 2;
  float4 s0 = ps[0], s1 = ps[1];
  int head = lane >> 3;
  bool leader = (lane & 7) == 0;
  for (int i = b; i < e2; i++) {
    int e = cs[i];
    int d = dst[e];
    const float4* pd = (const float4*)(fsrc + (size_t)d * HD) + lane * 2;
    float4 d0 = pd[0], d1 = pd[1];
    float dot = s0.x * d0.x + s0.y * d0.y + s0.z * d0.z + s0.w * d0.w
              + s1.x * d1.x + s1.y * d1.y + s1.z * d1.z + s1.w * d1.w;
    dot += __shfl_xor(dot, 1);
    dot += __shfl_xor(dot, 2);
    dot += __shfl_xor(dot, 4);
    if (leader) escore[(size_t)e * 8 + head] = dot;
    float x = leader ? dot * trans[e] : 0.f;
    x += __shfl_xor(x, 8);
    x += __shfl_xor(x, 16);
    x += __shfl_xor(x, 32);
    if (lane == 0) val[e] = x;
  }
}

// ---------------- wave-per-row top-10 threshold + run-combined values ----------------
__global__ __launch_bounds__(256) void topk_wave(const int* __restrict__ rp_s,
                                                 const int* __restrict__ keys_s,
                                                 const float* __restrict__ val,
                                                 float* __restrict__ aval,
                                                 float* __restrict__ thresh) {
  int wave = (blockIdx.x * blockDim.x + threadIdx.x) >> 6;
  int lane = threadIdx.x & 63;
  if (wave >= N_NODES) return;
  int b = rp_s[wave], e2 = rp_s[wave + 1];
  int len = e2 - b; if (len > 128) len = 128;
  float c[2];
#pragma unroll
  for (int k = 0; k < 2; k++) {
    int i = lane + 64 * k;
    float cv = 0.f;
    if (i < len) {
      int key = keys_s[b + i];
      int d = key >> 18;
      int prevd = (i == 0) ? -1 : (keys_s[b + i - 1] >> 18);
      if (d != prevd) {
        float s = val[key & EID_MASK];
        for (int j = i + 1; j < len; j++) {
          int kj = keys_s[b + j];
          if ((kj >> 18) != d) break;
          s += val[kj & EID_MASK];
        }
        cv = s;
        aval[b + i] = s;
      } else {
        aval[b + i] = 0.f;
      }
    }
    c[k] = cv;
  }
  float t10 = 0.f;
  for (int t = 0; t < 10; t++) {
    float m = fmaxf(c[0], c[1]);
#pragma unroll
    for (int off = 1; off < 64; off <<= 1) m = fmaxf(m, __shfl_xor(m, off));
    if (m <= 0.f) { t10 = 0.f; break; }
    t10 = m;
    if (t == 9) break;
    unsigned long long b0 = __ballot(c[0] == m);
    if (b0) {
      int l = __ffsll(b0) - 1;
      if (lane == l) c[0] = -1e30f;
    } else {
      unsigned long long b1 = __ballot(c[1] == m);
      int l = __ffsll(b1) - 1;
      if (lane == l) c[1] = -1e30f;
    }
  }
  if (lane == 0) thresh[wave] = fmaxf(t10, 0.f);
}

// ---------------- per-edge reverse-pair mask via binary search ----------------
__global__ __launch_bounds__(256) void cond_edges(const int* __restrict__ src, const int* __restrict__ dst,
                                                  const int* __restrict__ rp_s,
                                                  const int* __restrict__ keys_s,
                                                  const float* __restrict__ aval,
                                                  const float* __restrict__ thresh,
                                                  unsigned char* __restrict__ cond) {
  int e = blockIdx.x * blockDim.x + threadIdx.x;
  if (e >= N_EDGES) return;
  int s = src[e], d = dst[e];
  int lo = rp_s[d], hi = rp_s[d + 1];
  int end = hi;
  int target = s << 18;
  while (lo < hi) {
    int mid = (lo + hi) >> 1;
    if (keys_s[mid] < target) lo = mid + 1; else hi = mid;
  }
  float a = 0.f;
  if (lo < end && (keys_s[lo] >> 18) == s) a = aval[lo];
  cond[e] = (a < thresh[d]) ? 1 : 0;
}

// ---------------- per-dst-node: mask + edge softmax + aggregation (bf16 gather) ----------------
__global__ __launch_bounds__(64) void dst_softmax_agg(const int* __restrict__ rp_d, const int* __restrict__ cd,
                                                      const int* __restrict__ src,
                                                      const unsigned char* __restrict__ cond,
                                                      const float* __restrict__ escore,
                                                      const ushort* __restrict__ fsrc16,
                                                      float* __restrict__ out) {
  __shared__ float p_lds[MAXD * 9];
  __shared__ int u_lds[MAXD];
  int v = blockIdx.x;
  int lane = threadIdx.x;
  int rb = rp_d[v], re = rp_d[v + 1];
  int d = re - rb;
  if (d > MAXD) d = MAXD;

  float sc[2][8];
  float m[8];
#pragma unroll
  for (int h = 0; h < 8; h++) m[h] = -3.0e38f;

#pragma unroll
  for (int k = 0; k < 2; k++) {
    int il = lane + 64 * k;
    if (il < d) {
      int ei = cd[rb + il];
      int u = src[ei];
      u_lds[il] = u;
      bool cmask = cond[ei] != 0;
      const float* sp = escore + (size_t)ei * 8;
      float4 s0 = *(const float4*)sp;
      float4 s1 = *(const float4*)(sp + 4);
      float ss[8] = {s0.x, s0.y, s0.z, s0.w, s1.x, s1.y, s1.z, s1.w};
#pragma unroll
      for (int h = 0; h < 8; h++) {
        float x = cmask ? NEG_INF : ss[h];
        sc[k][h] = x;
        m[h] = fmaxf(m[h], x);
      }
    } else {
#pragma unroll
      for (int h = 0; h < 8; h++) sc[k][h] = -3.0e38f;
    }
  }
#pragma unroll
  for (int off = 1; off < 64; off <<= 1)
#pragma unroll
    for (int h = 0; h < 8; h++) m[h] = fmaxf(m[h], __shfl_xor(m[h], off));

  float z[8];
#pragma unroll
  for (int h = 0; h < 8; h++) z[h] = 0.f;
#pragma unroll
  for (int k = 0; k < 2; k++) {
    int il = lane + 64 * k;
    if (il < d) {
#pragma unroll
      for (int h = 0; h < 8; h++) {
        float p = expf(sc[k][h] - m[h]);
        z[h] += p;
        p_lds[il * 9 + h] = p;
      }
    }
  }
#pragma unroll
  for (int off = 1; off < 64; off <<= 1)
#pragma unroll
    for (int h = 0; h < 8; h++) z[h] += __shfl_xor(z[h], off);

  int myh = lane >> 3;
  float zh = 0.f;
#pragma unroll
  for (int h = 0; h < 8; h++) zh = (h == myh) ? z[h] : zh;
  float invZ = (d > 0) ? (1.0f / zh) : 0.f;

  __syncthreads();

  float acc[8];
#pragma unroll
  for (int j = 0; j < 8; j++) acc[j] = 0.f;
  for (int i = 0; i < d; i++) {
    float w = p_lds[i * 9 + myh] * invZ;
    const ushort* fp = fsrc16 + (size_t)u_lds[i] * HD + lane * 8;
    uint4 q = *(const uint4*)fp;
    acc[0] = fmaf(w, __uint_as_float(q.x << 16), acc[0]);
    acc[1] = fmaf(w, __uint_as_float(q.x & 0xFFFF0000u), acc[1]);
    acc[2] = fmaf(w, __uint_as_float(q.y << 16), acc[2]);
    acc[3] = fmaf(w, __uint_as_float(q.y & 0xFFFF0000u), acc[3]);
    acc[4] = fmaf(w, __uint_as_float(q.z << 16), acc[4]);
    acc[5] = fmaf(w, __uint_as_float(q.z & 0xFFFF0000u), acc[5]);
    acc[6] = fmaf(w, __uint_as_float(q.w << 16), acc[6]);
    acc[7] = fmaf(w, __uint_as_float(q.w & 0xFFFF0000u), acc[7]);
  }
  float* op = out + (size_t)v * HD + lane * 8;
  *(float4*)op = make_float4(acc[0], acc[1], acc[2], acc[3]);
  *(float4*)(op + 4) = make_float4(acc[4], acc[5], acc[6], acc[7]);
}

extern "C" void kernel_launch(void* const* d_in, const int* in_sizes, int n_in,
                              void* d_out, int out_size, void* d_ws, size_t ws_size,
                              hipStream_t stream) {
  const float* feat = (const float*)d_in[0];
  const float* fcw = (const float*)d_in[1];
  const float* trans = (const float*)d_in[2];
  const int* src = (const int*)d_in[3];
  const int* dst = (const int*)d_in[4];
  float* out = (float*)d_out;

  char* ws = (char*)d_ws;
  size_t off = 0;
  auto alloc = [&](size_t bytes) -> void* {
    size_t o = off;
    off = (off + bytes + 255) & ~(size_t)255;
    return (void*)(ws + o);
  };
  float* fsrc = (float*)alloc((size_t)N_NODES * HD * 4);
  ushort* fsrc16 = (ushort*)alloc((size_t)N_NODES * HD * 2);
  float* escore = (float*)alloc((size_t)N_EDGES * 8 * 4);
  float* val = (float*)alloc((size_t)N_EDGES * 4);
  int* cnt = (int*)alloc((size_t)4 * N_NODES * 4);
  int* rp_s = (int*)alloc((size_t)(N_NODES + 1) * 4);
  int* rp_d = (int*)alloc((size_t)(N_NODES + 1) * 4);
  int* cs = (int*)alloc((size_t)N_EDGES * 4);
  int* cd = (int*)alloc((size_t)N_EDGES * 4);
  int* keys_s = (int*)alloc((size_t)N_EDGES * 4);
  float* aval = (float*)alloc((size_t)N_EDGES * 4);
  float* thresh = (float*)alloc((size_t)N_NODES * 4);
  unsigned char* cond = (unsigned char*)alloc((size_t)N_EDGES);
  if (off > ws_size) return;

  int* cnt_s = cnt;
  int* cnt_d = cnt + N_NODES;
  int* fill_s = cnt + 2 * N_NODES;
  int* fill_d = cnt + 3 * N_NODES;

  hipMemsetAsync(cnt, 0, (size_t)4 * N_NODES * 4, stream);
  histo<<<N_EDGES / 256, 256, 0, stream>>>(src, dst, cnt_s, cnt_d);
  scan2<<<2, 1024, 0, stream>>>(cnt_s, cnt_d, rp_s, rp_d);
  scatter_csr<<<N_EDGES / 256, 256, 0, stream>>>(src, dst, rp_s, rp_d, fill_s, fill_d, cs, cd);
  sort_rows_bitonic<<<(2 * N_NODES * 64) / 256, 256, 0, stream>>>(rp_s, rp_d, dst, cs, cd, keys_s);
  gemm_nt<<<dim3(N_NODES / 128, HD / 128), 512, 0, stream>>>(feat, fcw, fsrc, fsrc16);
  edge_scores_row<<<(N_NODES * 64) / 256, 256, 0, stream>>>(fsrc, dst, trans, rp_s, cs, escore, val);
  topk_wave<<<(N_NODES * 64) / 256, 256, 0, stream>>>(rp_s, keys_s, val, aval, thresh);
  cond_edges<<<N_EDGES / 256, 256, 0, stream>>>(src, dst, rp_s, keys_s, aval, thresh, cond);
  dst_softmax_agg<<<N_NODES, 64, 0, stream>>>(rp_d, cd, src, cond, escore, fsrc16, out);
}